// Round 8
// baseline (1769.446 us; speedup 1.0000x reference)
//
#include <hip/hip_runtime.h>

// Autoregressive masked net sampler:
//  - output col i == sampling-time x[:,i]  (masks: out i depends on spins < i only)
//  - spin blocks of KB=16: history = dense MFMA GEMM (B-stream bytes ~ Sum 20I:
//    KB=16 cuts it 57% vs KB=8), intra-block = per-row sequential MFMA (R7).
// R7 lesson: gemm was latency-bound (7 dependent loads : 10 MFMAs per kstep).
// R8: KB=16 + 80Mx64N wave tile (20 MFMA/kstep) + depth-2 B register prefetch +
// f16 Zg (halves Zg round-trip; logits |z|<~3 -> f16 err ~3e-4/activation).

#define NS   64          // spins
#define HC   20          // hidden channels per spin
#define HTOT 1280        // NS*HC
#define NB   16384       // batch
#define KB   16          // spins per block (4 blocks)
#define BT   16          // batch rows per seq workgroup (single wave)
#define W6R  80          // W6p padded rows
#define ALP  344         // aL row pad (f16): 344*2=688B = 172 words = 12 mod 32 -> 2-way (free)
#define SLP  88          // sL row pad: 176B = 44 words = 12 mod 32 -> 2-way
#define ZGROWS (4*320 + 16)  // 1296: 1280 written rows + pad (discarded OOR reads)

typedef _Float16 f16;
typedef _Float16 f16x4 __attribute__((ext_vector_type(4)));
typedef _Float16 f16x8 __attribute__((ext_vector_type(8)));
typedef float f32x4 __attribute__((ext_vector_type(4)));

static __device__ __forceinline__ f32x4 mfma16(f16x8 a, f16x8 b, f32x4 c) {
  return __builtin_amdgcn_mfma_f32_16x16x32_f16(a, b, c, 0, 0, 0);
}

static __device__ __forceinline__ float sigm(float z) {
  return __builtin_amdgcn_rcpf(1.0f + __expf(-z));
}

// ---------------------------------------------------------------------------
// prep1: masked, spin-major-permuted f16 weights.
//  Wp [L=0..3][cp][xp]  cp=j_o*20+ch_o, xp=j_i*20+ch_i, mask j_i <= j_o
//  W1p[cp][j_i]         mask j_i < j_o (exclusive)
//  W6p[i][xp]           mask j_i <= i (rows 64..79 zero)
// ---------------------------------------------------------------------------
__global__ __launch_bounds__(256) void prep1(
    const float* __restrict__ W1, const float* __restrict__ W2,
    const float* __restrict__ W3, const float* __restrict__ W4,
    const float* __restrict__ W5, const float* __restrict__ W6,
    f16* __restrict__ Wp, f16* __restrict__ W1p, f16* __restrict__ W6p) {
  __shared__ float row[HTOT];
  int bid = blockIdx.x;
  if (bid < 4 * HTOT) {
    int L = bid / HTOT, cp = bid % HTOT;
    int j_o = cp / HC, ch_o = cp % HC;
    const float* Wsrc = (L == 0) ? W2 : (L == 1) ? W3 : (L == 2) ? W4 : W5;
    const float* src = Wsrc + (size_t)(ch_o * NS + j_o) * HTOT;
    for (int k = threadIdx.x; k < HTOT; k += 256) row[k] = src[k];
    __syncthreads();
    f16* dst = Wp + (size_t)bid * HTOT;
    for (int xp = threadIdx.x; xp < HTOT; xp += 256) {
      int j_i = xp / HC, ch_i = xp % HC;
      float v = (j_i <= j_o) ? row[ch_i * NS + j_i] : 0.0f;
      dst[xp] = (f16)v;
    }
  } else if (bid < 4 * HTOT + 320) {
    int rr = (bid - 4 * HTOT) * 4 + (threadIdx.x >> 6);
    int c = threadIdx.x & 63;
    int j_o = rr / HC, ch_o = rr % HC;
    float v = (c < j_o) ? W1[(size_t)(ch_o * NS + j_o) * NS + c] : 0.0f;
    W1p[(size_t)rr * NS + c] = (f16)v;
  } else {
    int i = bid - (4 * HTOT + 320);
    if (i < NS) {
      const float* src = W6 + (size_t)i * HTOT;
      for (int k = threadIdx.x; k < HTOT; k += 256) row[k] = src[k];
      __syncthreads();
      for (int xp = threadIdx.x; xp < HTOT; xp += 256) {
        int j_i = xp / HC, ch_i = xp % HC;
        float v = (j_i <= i) ? row[ch_i * NS + j_i] : 0.0f;
        W6p[(size_t)i * HTOT + xp] = (f16)v;
      }
    } else {
      for (int xp = threadIdx.x; xp < HTOT; xp += 256)
        W6p[(size_t)i * HTOT + xp] = (f16)0.0f;
    }
  }
}

// ---------------------------------------------------------------------------
// prep2: seq A-operand repacks (zero-padded -> compile-time K/M trips exact).
//  Wsq[L][i][chp<32][kk<320] = chp<20 ? Wp[L][i*20+chp][SB*20+kk] : 0, SB=(i/16)*16
//  W1sq[i][chp<32][j<64]     = chp<20 ? W1p[i*20+chp][j] : 0
// ---------------------------------------------------------------------------
__global__ __launch_bounds__(256) void prep2(
    const f16* __restrict__ Wp, const f16* __restrict__ W1p,
    f16* __restrict__ Wsq, f16* __restrict__ W1sq) {
  int bid = blockIdx.x;
  if (bid < 256) {
    int L = bid >> 6, i = bid & 63;
    int SB = (i >> 4) << 4;
    const f16* src = Wp + ((size_t)L * HTOT + i * HC) * HTOT + SB * HC;
    f16* dst = Wsq + (size_t)bid * 32 * 320;
    for (int el = threadIdx.x; el < 32 * 320; el += 256) {
      int chp = el / 320, kk = el % 320;
      dst[el] = (chp < HC) ? src[(size_t)chp * HTOT + kk] : (f16)0.0f;
    }
  } else {
    int i = bid - 256;
    const f16* src = W1p + (size_t)(i * HC) * NS;
    f16* dst = W1sq + (size_t)i * 32 * 64;
    for (int el = threadIdx.x; el < 32 * 64; el += 256) {
      int chp = el >> 6, j = el & 63;
      dst[el] = (chp < HC) ? src[(size_t)chp * NS + j] : (f16)0.0f;
    }
  }
}

// ---------------------------------------------------------------------------
// gemm_block_mfma (KB=16): history GEMMs for block starting at spin I.
//  y<4: Zg[L][c][b] = sum_{k<20I} Wp[L][20I+c][k] * AH[L][k][b], c<320 (f16 out)
//  y=4: Zg6[t][b]   = sum_{k<20I} W6p[I+t][k]    * AH[4][k][b], t<16 (f32 out)
// 4 waves, each 80 M rows x 64 N cols: 20 MFMA : 5 A-loads (L2-resident Wp,
// just-in-time) + 4 B-loads (HBM stream, depth-2 register prefetch).
// I==0: G32=0 -> writes zeros (initializes Zg/Zg6; d_ws is poisoned each call).
// ---------------------------------------------------------------------------
__global__ __launch_bounds__(256) void gemm_block_mfma(
    const f16* __restrict__ Wp, const f16* __restrict__ W6p,
    const f16* __restrict__ AH, f16* __restrict__ Zg,
    float* __restrict__ Zg6, int I, int BS) {
  const int L = blockIdx.y;
  const int wv = threadIdx.x >> 6;
  const int l15 = threadIdx.x & 15;
  const int quad = (threadIdx.x & 63) >> 4;
  const int G32 = (HC * I) >> 5;

  if (L < 4) {
    const int b0 = blockIdx.x * 64;
    f32x4 acc[5][4];
#pragma unroll
    for (int mt = 0; mt < 5; ++mt)
#pragma unroll
      for (int nt = 0; nt < 4; ++nt) acc[mt][nt] = (f32x4){0.f, 0.f, 0.f, 0.f};

    const f16* aptr = Wp + (size_t)(L * HTOT + HC * I + wv * 80 + l15) * HTOT + quad * 8;
    const f16* bptr = AH + ((size_t)(L * 160 + quad) * BS + b0 + l15) * 8;
    const size_t bstep = (size_t)4 * BS * 8;

    f16x8 bc[4];
    if (G32 > 0) {
#pragma unroll
      for (int nt = 0; nt < 4; ++nt) bc[nt] = *(const f16x8*)(bptr + nt * 128);
    }
    for (int ks = 0; ks < G32; ++ks) {
      f16x8 bn[4];
      if (ks + 1 < G32) {
        const f16* bp2 = bptr + (size_t)(ks + 1) * bstep;
#pragma unroll
        for (int nt = 0; nt < 4; ++nt) bn[nt] = *(const f16x8*)(bp2 + nt * 128);
      }
      f16x8 af[5];
#pragma unroll
      for (int mt = 0; mt < 5; ++mt)
        af[mt] = *(const f16x8*)(aptr + (size_t)(mt * 16) * HTOT + ks * 32);
#pragma unroll
      for (int mt = 0; mt < 5; ++mt)
#pragma unroll
        for (int nt = 0; nt < 4; ++nt) acc[mt][nt] = mfma16(af[mt], bc[nt], acc[mt][nt]);
      if (ks + 1 < G32) {
#pragma unroll
        for (int nt = 0; nt < 4; ++nt) bc[nt] = bn[nt];
      }
    }
#pragma unroll
    for (int mt = 0; mt < 5; ++mt)
#pragma unroll
      for (int nt = 0; nt < 4; ++nt)
#pragma unroll
        for (int rg = 0; rg < 4; ++rg) {
          int c = wv * 80 + mt * 16 + quad * 4 + rg;
          int b = b0 + nt * 16 + l15;
          Zg[(size_t)(L * 320 + c) * BS + b] = (f16)acc[mt][nt][rg];
        }
  } else {
    // layer-6 slice: M=16 tile over W6p rows I..I+15, all 16 stored
    const int b0 = blockIdx.x * 64 + wv * 16;
    f32x4 acc = (f32x4){0.f, 0.f, 0.f, 0.f};
    const f16* aptr = W6p + (size_t)(I + l15) * HTOT + quad * 8;
    const f16* bptr = AH + ((size_t)(4 * 160 + quad) * BS + b0 + l15) * 8;
    const size_t bstep = (size_t)4 * BS * 8;
    f16x8 bc;
    if (G32 > 0) bc = *(const f16x8*)bptr;
    for (int ks = 0; ks < G32; ++ks) {
      f16x8 bn;
      if (ks + 1 < G32) bn = *(const f16x8*)(bptr + (size_t)(ks + 1) * bstep);
      f16x8 af = *(const f16x8*)(aptr + ks * 32);
      acc = mfma16(af, bc, acc);
      if (ks + 1 < G32) bc = bn;
    }
#pragma unroll
    for (int rg = 0; rg < 4; ++rg)
      Zg6[(size_t)(quad * 4 + rg) * BS + b0 + l15] = acc[rg];
  }
}

// ---------------------------------------------------------------------------
// seq_block (KB=16, MFMA, single wave, BT=16 rows): per t: L1 (2 Ksteps) ->
// L2..L5 (C2N Ksteps + f16 Zg at end) -> z6 (C2N Ksteps) -> sample.
// C2N = ceil(20(t+1)/32) grouped {t<4:3, t<8:5, t<12:8, t<16:10}; zero-padded
// Wsq/W1sq/aL/sL make fixed trips exact. Zg6/u loaded at t-start (latency hidden).
// ---------------------------------------------------------------------------
template <int C2N>
static __device__ __forceinline__ void seq_steps(
    int T0, int T1, int I, int r, int quad, int l15, int lane, int brel, int bg,
    int BS, const f16* __restrict__ Wsq, const f16* __restrict__ W1sq,
    const f16* __restrict__ W6p, const f16* __restrict__ Zg,
    const float* __restrict__ Zg6, const float* __restrict__ u,
    float* __restrict__ outp, f16 (&aL)[5][BT][ALP], f16 (&sL)[BT][SLP]) {
#pragma unroll 1
  for (int t = T0; t < T1; ++t) {
    const int i = I + t;
    float z6hist = Zg6[(size_t)t * BS + brel];  // early loads, used at t-end
    float uu = u[(size_t)i * NB + bg];

    // ---- layer 1: A = W1sq[i] (2 M-tiles), B = sL (K=64) ----
    {
      const f16* a0 = W1sq + ((size_t)i * 32 + l15) * 64 + quad * 8;
      f16x8 b0v = *(const f16x8*)&sL[r][quad * 8];
      f16x8 b1v = *(const f16x8*)&sL[r][32 + quad * 8];
      f16x8 a00 = *(const f16x8*)(a0);
      f16x8 a01 = *(const f16x8*)(a0 + 32);
      f16x8 a10 = *(const f16x8*)(a0 + 16 * 64);
      f16x8 a11 = *(const f16x8*)(a0 + 16 * 64 + 32);
      f32x4 acc0 = {0.f, 0.f, 0.f, 0.f}, acc1 = {0.f, 0.f, 0.f, 0.f};
      acc0 = mfma16(a00, b0v, acc0);
      acc0 = mfma16(a01, b1v, acc0);
      acc1 = mfma16(a10, b0v, acc1);
      acc1 = mfma16(a11, b1v, acc1);
      f16x4 v0;
#pragma unroll
      for (int rg = 0; rg < 4; ++rg) v0[rg] = (f16)sigm(acc0[rg]);
      *(f16x4*)&aL[0][r][t * HC + quad * 4] = v0;
      if (quad == 0) {
        f16x4 v1;
#pragma unroll
        for (int rg = 0; rg < 4; ++rg) v1[rg] = (f16)sigm(acc1[rg]);
        *(f16x4*)&aL[0][r][t * HC + 16] = v1;
      }
    }
    __syncthreads();

    // ---- layers 2..5: A = Wsq[L][i], B = aL[L], + f16 Zg at chain end ----
#pragma unroll 1
    for (int L = 0; L < 4; ++L) {
      float zin0[4], zin1[4];
#pragma unroll
      for (int rg = 0; rg < 4; ++rg)
        zin0[rg] = (float)Zg[(size_t)(L * 320 + t * HC + quad * 4 + rg) * BS + brel];
#pragma unroll
      for (int rg = 0; rg < 4; ++rg)
        zin1[rg] = (float)Zg[(size_t)(L * 320 + t * HC + 16 + quad * 4 + rg) * BS + brel];
      const f16* abase = Wsq + (((size_t)L * 64 + i) * 32 + l15) * 320;
      const f16* lrow = &aL[L][r][0];
      f32x4 acc0 = {0.f, 0.f, 0.f, 0.f}, acc1 = {0.f, 0.f, 0.f, 0.f};
#pragma unroll
      for (int ks = 0; ks < C2N; ++ks) {
        f16x8 bv = *(const f16x8*)(lrow + ks * 32 + quad * 8);
        f16x8 a0 = *(const f16x8*)(abase + ks * 32 + quad * 8);
        f16x8 a1 = *(const f16x8*)(abase + 16 * 320 + ks * 32 + quad * 8);
        acc0 = mfma16(a0, bv, acc0);
        acc1 = mfma16(a1, bv, acc1);
      }
      f16x4 v0;
#pragma unroll
      for (int rg = 0; rg < 4; ++rg) v0[rg] = (f16)sigm(zin0[rg] + acc0[rg]);
      *(f16x4*)&aL[L + 1][r][t * HC + quad * 4] = v0;
      if (quad == 0) {
        f16x4 v1;
#pragma unroll
        for (int rg = 0; rg < 4; ++rg) v1[rg] = (f16)sigm(zin1[rg] + acc1[rg]);
        *(f16x4*)&aL[L + 1][r][t * HC + 16] = v1;
      }
      __syncthreads();
    }

    // ---- z6 intra: A = W6p rows i+l15 (m=0 used), B = aL[4] ----
    {
      const f16* w6b = W6p + (size_t)(i + l15) * HTOT + HC * I;
      const f16* l5 = &aL[4][r][0];
      f32x4 a6 = {0.f, 0.f, 0.f, 0.f};
#pragma unroll
      for (int ks = 0; ks < C2N; ++ks) {
        f16x8 bv = *(const f16x8*)(l5 + ks * 32 + quad * 8);
        f16x8 av = *(const f16x8*)(w6b + ks * 32 + quad * 8);
        a6 = mfma16(av, bv, a6);
      }
      if (quad == 0) {
        float x = sigm(a6[0] + z6hist);
        outp[(size_t)bg * NS + i] = x;  // final output col i == sampling-time x
        sL[r][i] = (f16)((x >= uu) ? 1.0f : -1.0f);
      }
    }
    __syncthreads();
  }
}

__global__ __launch_bounds__(64, 1) void seq_block(
    const f16* __restrict__ Wsq, const f16* __restrict__ W1sq,
    const f16* __restrict__ W6p, f16* __restrict__ AH,
    const f16* __restrict__ Zg, const float* __restrict__ Zg6,
    f16* __restrict__ s_ws, const float* __restrict__ u,
    float* __restrict__ outp, int I, int BS, int b0) {
  __shared__ __align__(16) f16 aL[5][BT][ALP];   // 55040 B
  __shared__ __align__(16) f16 sL[BT][SLP];      // 2816 B -> 57856 total, 2 WG/CU

  const int lane = threadIdx.x;
  const int l15 = lane & 15;
  const int quad = lane >> 4;
  const int r = l15;
  const int brel = blockIdx.x * BT + r;
  const int bg = b0 + brel;

  // zero LDS (unwritten regions must multiply as exact 0)
  {
    f16x8 z = {};
    f16x8* pa = (f16x8*)&aL[0][0][0];
    for (int k = lane; k < (5 * BT * ALP) / 8; k += 64) pa[k] = z;
    f16x8* ps = (f16x8*)&sL[0][0];
    for (int k = lane; k < (BT * SLP) / 8; k += 64) ps[k] = z;
  }
  __syncthreads();

  // sampled-bit history j < I
  {
    const int nck = I >> 3;
    for (int idx = lane; idx < BT * nck; idx += 64) {
      int rr = idx & 15, c8 = idx >> 4;
      *(f16x8*)&sL[rr][c8 * 8] =
          *(const f16x8*)(s_ws + (size_t)(blockIdx.x * BT + rr) * NS + c8 * 8);
    }
  }
  __syncthreads();

  seq_steps<3>(0, 4, I, r, quad, l15, lane, brel, bg, BS, Wsq, W1sq, W6p, Zg,
               Zg6, u, outp, aL, sL);
  seq_steps<5>(4, 8, I, r, quad, l15, lane, brel, bg, BS, Wsq, W1sq, W6p, Zg,
               Zg6, u, outp, aL, sL);
  seq_steps<8>(8, 12, I, r, quad, l15, lane, brel, bg, BS, Wsq, W1sq, W6p, Zg,
               Zg6, u, outp, aL, sL);
  seq_steps<10>(12, 16, I, r, quad, l15, lane, brel, bg, BS, Wsq, W1sq, W6p, Zg,
                Zg6, u, outp, aL, sL);

  // ---- bulk writeout: aL -> AH ([L][g][b][e8]), sampled bits -> s_ws ----
  for (int w = lane; w < 5 * 40 * BT; w += 64) {
    int rr = w & 15;
    int q8 = w >> 4;
    int L = q8 / 40, x8 = q8 % 40;
    f16x8 v = *(const f16x8*)&aL[L][rr][x8 * 8];
    int gg = ((HC * I) >> 3) + x8;
    *(f16x8*)(AH + ((size_t)(L * 160 + gg) * BS + blockIdx.x * BT + rr) * 8) = v;
  }
  if (lane < BT) {
    int rowb = blockIdx.x * BT + lane;
    *(f16x8*)(s_ws + (size_t)rowb * NS + I) = *(const f16x8*)&sL[lane][I];
    *(f16x8*)(s_ws + (size_t)rowb * NS + I + 8) = *(const f16x8*)&sL[lane][I + 8];
  }
}

// ---------------------------------------------------------------------------
extern "C" void kernel_launch(void* const* d_in, const int* in_sizes, int n_in,
                              void* d_out, int out_size, void* d_ws, size_t ws_size,
                              hipStream_t stream) {
  (void)in_sizes; (void)n_in; (void)out_size;
  const float* u  = (const float*)d_in[1];
  const float* W1 = (const float*)d_in[2];
  const float* W2 = (const float*)d_in[3];
  const float* W3 = (const float*)d_in[4];
  const float* W4 = (const float*)d_in[5];
  const float* W5 = (const float*)d_in[6];
  const float* W6 = (const float*)d_in[7];
  float* outp = (float*)d_out;

  const size_t wpEls   = (size_t)4 * HTOT * HTOT;    // 6,553,600
  const size_t w1Els   = (size_t)HTOT * NS;          // 81,920
  const size_t w6Els   = (size_t)W6R * HTOT;         // 102,400
  const size_t wsqEls  = (size_t)4 * 64 * 32 * 320;  // 2,621,440
  const size_t w1sqEls = (size_t)64 * 32 * 64;       // 131,072
  const size_t wBytes = (wpEls + w1Els + w6Els + wsqEls + w1sqEls) * sizeof(f16);
  // per-row bytes: AH 12800 + Zg f16 2592 + Zg6 64 + s 128 = 15584
  size_t rem = (ws_size > wBytes + 4096) ? (ws_size - wBytes - 4096) : 0;
  long long bs = (long long)(rem / 15600);
  bs = (bs / 64) * 64;
  if (bs > NB) bs = NB;
  if (bs < 64) bs = 64;
  const int BS = (int)bs;

  f16* Wp   = (f16*)d_ws;
  f16* W1p  = Wp + wpEls;
  f16* W6p  = W1p + w1Els;
  f16* Wsq  = W6p + w6Els;
  f16* W1sq = Wsq + wsqEls;
  f16* AH   = W1sq + w1sqEls;                        // 5*160*BS*8 f16
  f16* Zg   = AH + (size_t)5 * 160 * BS * 8;         // ZGROWS*BS f16
  float* Zg6 = (float*)(Zg + (size_t)ZGROWS * BS);   // 16*BS f32
  f16* s_ws  = (f16*)(Zg6 + (size_t)16 * BS);        // BS*64 f16

  prep1<<<dim3(4 * HTOT + 320 + W6R), dim3(256), 0, stream>>>(
      W1, W2, W3, W4, W5, W6, Wp, W1p, W6p);
  prep2<<<dim3(256 + 64), dim3(256), 0, stream>>>(Wp, W1p, Wsq, W1sq);

  for (int c0 = 0; c0 < NB; c0 += BS) {
    int nr = NB - c0; if (nr > BS) nr = BS;
    for (int m = 0; m < NS / KB; ++m) {
      const int I = m * KB;
      gemm_block_mfma<<<dim3(nr / 64, 5), dim3(256), 0, stream>>>(
          Wp, W6p, AH, Zg, Zg6, I, BS);
      seq_block<<<dim3(nr / BT), dim3(64), 0, stream>>>(
          Wsq, W1sq, W6p, AH, Zg, Zg6, s_ws, u, outp, I, BS, c0);
    }
  }
}

// Round 9
// 1408.711 us; speedup vs baseline: 1.2561x; 1.2561x over previous
//
#include <hip/hip_runtime.h>

// Autoregressive masked net sampler — hierarchical history (R9):
//  - output col i == sampling-time x[:,i]
//  - per 16-spin block: gemm_full (KB=16 stride: B-bytes -57% vs KB=8, 80Mx64N
//    wave tile + depth-2 B prefetch) covers K < 20*I16 for all 320 channels;
//    seq runs 8-spin sub-blocks exactly like R7 (window 160, LDS 29KB, 5 WG/CU,
//    8-step chain); gemm_mid (K=160 fixed) bridges the middle-8 history.
// R8 lesson: KB=16 seq -> 57.9KB LDS -> 2 rounds x 2x chain = 2x seq time.

#define NS   64          // spins
#define HC   20          // hidden channels per spin
#define HTOT 1280        // NS*HC
#define NB   16384       // batch
#define BT   16          // batch rows per seq workgroup (single wave)
#define W6R  80          // W6p padded rows
#define ZGROWS (4*320 + 16)  // f16 Zg rows + pad (seq mt=1 lanes over-read, discarded)

typedef _Float16 f16;
typedef _Float16 f16x4 __attribute__((ext_vector_type(4)));
typedef _Float16 f16x8 __attribute__((ext_vector_type(8)));
typedef float f32x4 __attribute__((ext_vector_type(4)));

static __device__ __forceinline__ f32x4 mfma16(f16x8 a, f16x8 b, f32x4 c) {
  return __builtin_amdgcn_mfma_f32_16x16x32_f16(a, b, c, 0, 0, 0);
}

static __device__ __forceinline__ float sigm(float z) {
  return __builtin_amdgcn_rcpf(1.0f + __expf(-z));
}

// ---------------------------------------------------------------------------
// prep1: masked, spin-major-permuted f16 weights.
//  Wp [L=0..3][cp][xp]  cp=j_o*20+ch_o, xp=j_i*20+ch_i, mask j_i <= j_o
//  W1p[cp][j_i]         mask j_i < j_o (exclusive)
//  W6p[i][xp]           mask j_i <= i (rows 64..79 zero)
// ---------------------------------------------------------------------------
__global__ __launch_bounds__(256) void prep1(
    const float* __restrict__ W1, const float* __restrict__ W2,
    const float* __restrict__ W3, const float* __restrict__ W4,
    const float* __restrict__ W5, const float* __restrict__ W6,
    f16* __restrict__ Wp, f16* __restrict__ W1p, f16* __restrict__ W6p) {
  __shared__ float row[HTOT];
  int bid = blockIdx.x;
  if (bid < 4 * HTOT) {
    int L = bid / HTOT, cp = bid % HTOT;
    int j_o = cp / HC, ch_o = cp % HC;
    const float* Wsrc = (L == 0) ? W2 : (L == 1) ? W3 : (L == 2) ? W4 : W5;
    const float* src = Wsrc + (size_t)(ch_o * NS + j_o) * HTOT;
    for (int k = threadIdx.x; k < HTOT; k += 256) row[k] = src[k];
    __syncthreads();
    f16* dst = Wp + (size_t)bid * HTOT;
    for (int xp = threadIdx.x; xp < HTOT; xp += 256) {
      int j_i = xp / HC, ch_i = xp % HC;
      float v = (j_i <= j_o) ? row[ch_i * NS + j_i] : 0.0f;
      dst[xp] = (f16)v;
    }
  } else if (bid < 4 * HTOT + 320) {
    int rr = (bid - 4 * HTOT) * 4 + (threadIdx.x >> 6);
    int c = threadIdx.x & 63;
    int j_o = rr / HC, ch_o = rr % HC;
    float v = (c < j_o) ? W1[(size_t)(ch_o * NS + j_o) * NS + c] : 0.0f;
    W1p[(size_t)rr * NS + c] = (f16)v;
  } else {
    int i = bid - (4 * HTOT + 320);
    if (i < NS) {
      const float* src = W6 + (size_t)i * HTOT;
      for (int k = threadIdx.x; k < HTOT; k += 256) row[k] = src[k];
      __syncthreads();
      for (int xp = threadIdx.x; xp < HTOT; xp += 256) {
        int j_i = xp / HC, ch_i = xp % HC;
        float v = (j_i <= i) ? row[ch_i * NS + j_i] : 0.0f;
        W6p[(size_t)i * HTOT + xp] = (f16)v;
      }
    } else {
      for (int xp = threadIdx.x; xp < HTOT; xp += 256)
        W6p[(size_t)i * HTOT + xp] = (f16)0.0f;
    }
  }
}

// ---------------------------------------------------------------------------
// prep2: seq A-operand repacks (zero-padded -> fixed K/M trips exact).
//  Wsq[L][i][chp<32][kk<160] = chp<20 ? Wp[L][i*20+chp][(i/8)*160 + kk] : 0
//  W1sq[i][chp<32][j<64]     = chp<20 ? W1p[i*20+chp][j] : 0
// ---------------------------------------------------------------------------
__global__ __launch_bounds__(256) void prep2(
    const f16* __restrict__ Wp, const f16* __restrict__ W1p,
    f16* __restrict__ Wsq, f16* __restrict__ W1sq) {
  int bid = blockIdx.x;
  if (bid < 256) {
    int L = bid >> 6, i = bid & 63;
    const f16* src = Wp + ((size_t)L * HTOT + i * HC) * HTOT + (i >> 3) * 160;
    f16* dst = Wsq + (size_t)bid * 32 * 160;
    for (int el = threadIdx.x; el < 32 * 160; el += 256) {
      int chp = el / 160, kk = el % 160;
      dst[el] = (chp < HC) ? src[(size_t)chp * HTOT + kk] : (f16)0.0f;
    }
  } else {
    int i = bid - 256;
    const f16* src = W1p + (size_t)(i * HC) * NS;
    f16* dst = W1sq + (size_t)i * 32 * 64;
    for (int el = threadIdx.x; el < 32 * 64; el += 256) {
      int chp = el >> 6, j = el & 63;
      dst[el] = (chp < HC) ? src[(size_t)chp * NS + j] : (f16)0.0f;
    }
  }
}

// ---------------------------------------------------------------------------
// gemm_full (I in {0,16,32,48}): history K < 20I for the 16-spin block at I.
//  y<4: Zg[L*320 + c][b] = sum_k Wp[L][20I+c][k]*AH[L][k][b], c<320 (f16 out)
//  y=4: Zg6[m][b]        = sum_k W6p[I+m][k]   *AH[4][k][b], m<16 (f32 out)
// 4 waves x (80M x 64N) = 20 MFMA : 9 loads per kstep, depth-2 B prefetch.
// I==0: G32=0 -> initializes Zg/Zg6 to zero (d_ws is poisoned each call).
// ---------------------------------------------------------------------------
__global__ __launch_bounds__(256) void gemm_full(
    const f16* __restrict__ Wp, const f16* __restrict__ W6p,
    const f16* __restrict__ AH, f16* __restrict__ Zg,
    float* __restrict__ Zg6, int I, int BS) {
  const int L = blockIdx.y;
  const int wv = threadIdx.x >> 6;
  const int l15 = threadIdx.x & 15;
  const int quad = (threadIdx.x & 63) >> 4;
  const int G32 = (HC * I) >> 5;

  if (L < 4) {
    const int b0 = blockIdx.x * 64;
    f32x4 acc[5][4];
#pragma unroll
    for (int mt = 0; mt < 5; ++mt)
#pragma unroll
      for (int nt = 0; nt < 4; ++nt) acc[mt][nt] = (f32x4){0.f, 0.f, 0.f, 0.f};

    const f16* aptr = Wp + (size_t)(L * HTOT + HC * I + wv * 80 + l15) * HTOT + quad * 8;
    const f16* bptr = AH + ((size_t)(L * 160 + quad) * BS + b0 + l15) * 8;
    const size_t bstep = (size_t)4 * BS * 8;

    f16x8 bc[4];
    if (G32 > 0) {
#pragma unroll
      for (int nt = 0; nt < 4; ++nt) bc[nt] = *(const f16x8*)(bptr + nt * 128);
    }
    for (int ks = 0; ks < G32; ++ks) {
      f16x8 bn[4];
      if (ks + 1 < G32) {
        const f16* bp2 = bptr + (size_t)(ks + 1) * bstep;
#pragma unroll
        for (int nt = 0; nt < 4; ++nt) bn[nt] = *(const f16x8*)(bp2 + nt * 128);
      }
      f16x8 af[5];
#pragma unroll
      for (int mt = 0; mt < 5; ++mt)
        af[mt] = *(const f16x8*)(aptr + (size_t)(mt * 16) * HTOT + ks * 32);
#pragma unroll
      for (int mt = 0; mt < 5; ++mt)
#pragma unroll
        for (int nt = 0; nt < 4; ++nt) acc[mt][nt] = mfma16(af[mt], bc[nt], acc[mt][nt]);
      if (ks + 1 < G32) {
#pragma unroll
        for (int nt = 0; nt < 4; ++nt) bc[nt] = bn[nt];
      }
    }
#pragma unroll
    for (int mt = 0; mt < 5; ++mt)
#pragma unroll
      for (int nt = 0; nt < 4; ++nt)
#pragma unroll
        for (int rg = 0; rg < 4; ++rg) {
          int c = wv * 80 + mt * 16 + quad * 4 + rg;
          int b = b0 + nt * 16 + l15;
          Zg[(size_t)(L * 320 + c) * BS + b] = (f16)acc[mt][nt][rg];
        }
  } else {
    const int b0 = blockIdx.x * 64 + wv * 16;
    f32x4 acc = (f32x4){0.f, 0.f, 0.f, 0.f};
    const f16* aptr = W6p + (size_t)(I + l15) * HTOT + quad * 8;
    const f16* bptr = AH + ((size_t)(4 * 160 + quad) * BS + b0 + l15) * 8;
    const size_t bstep = (size_t)4 * BS * 8;
    f16x8 bc;
    if (G32 > 0) bc = *(const f16x8*)bptr;
    for (int ks = 0; ks < G32; ++ks) {
      f16x8 bn;
      if (ks + 1 < G32) bn = *(const f16x8*)(bptr + (size_t)(ks + 1) * bstep);
      f16x8 af = *(const f16x8*)(aptr + ks * 32);
      acc = mfma16(af, bc, acc);
      if (ks + 1 < G32) bc = bn;
    }
#pragma unroll
    for (int rg = 0; rg < 4; ++rg)
      Zg6[(size_t)(quad * 4 + rg) * BS + b0 + l15] = acc[rg];
  }
}

// ---------------------------------------------------------------------------
// gemm_mid (I in {0,16,32,48}): middle-8 history, K window [20I, 20I+160),
// B = AH rows written by the even sub-block's seq. Accumulates (RMW) into
// Zg rows [160,320) and Zg6 rows [8,16). 128 threads = 2 waves (80M x 64N).
// 5 k-steps fully unrolled -> one latency exposure.
// ---------------------------------------------------------------------------
__global__ __launch_bounds__(128) void gemm_mid(
    const f16* __restrict__ Wp, const f16* __restrict__ W6p,
    const f16* __restrict__ AH, f16* __restrict__ Zg,
    float* __restrict__ Zg6, int I, int BS) {
  const int L = blockIdx.y;
  const int wv = threadIdx.x >> 6;  // 0..1
  const int l15 = threadIdx.x & 15;
  const int quad = (threadIdx.x & 63) >> 4;
  const int g0 = (HC * I) >> 3;
  const size_t bstep = (size_t)4 * BS * 8;

  if (L < 4) {
    const int b0 = blockIdx.x * 64;
    const f16* abase =
        Wp + (size_t)(L * HTOT + HC * (I + 8) + wv * 80 + l15) * HTOT + HC * I + quad * 8;
    const f16* bbase = AH + ((size_t)(L * 160 + g0 + quad) * BS + b0 + l15) * 8;
    f32x4 acc[5][4];
#pragma unroll
    for (int mt = 0; mt < 5; ++mt)
#pragma unroll
      for (int nt = 0; nt < 4; ++nt) acc[mt][nt] = (f32x4){0.f, 0.f, 0.f, 0.f};
#pragma unroll
    for (int ks = 0; ks < 5; ++ks) {
      f16x8 bf[4];
#pragma unroll
      for (int nt = 0; nt < 4; ++nt)
        bf[nt] = *(const f16x8*)(bbase + (size_t)ks * bstep + nt * 128);
      f16x8 af[5];
#pragma unroll
      for (int mt = 0; mt < 5; ++mt)
        af[mt] = *(const f16x8*)(abase + (size_t)(mt * 16) * HTOT + ks * 32);
#pragma unroll
      for (int mt = 0; mt < 5; ++mt)
#pragma unroll
        for (int nt = 0; nt < 4; ++nt) acc[mt][nt] = mfma16(af[mt], bf[nt], acc[mt][nt]);
    }
#pragma unroll
    for (int mt = 0; mt < 5; ++mt)
#pragma unroll
      for (int nt = 0; nt < 4; ++nt)
#pragma unroll
        for (int rg = 0; rg < 4; ++rg) {
          int c = wv * 80 + mt * 16 + quad * 4 + rg;
          size_t idx = (size_t)(L * 320 + 160 + c) * BS + b0 + nt * 16 + l15;
          Zg[idx] = (f16)((float)Zg[idx] + acc[mt][nt][rg]);
        }
  } else {
    const int b0 = blockIdx.x * 64 + wv * 32;
    const f16* abase = W6p + (size_t)(I + 8 + l15) * HTOT + HC * I + quad * 8;
    const f16* bbase = AH + ((size_t)(4 * 160 + g0 + quad) * BS + b0 + l15) * 8;
    f32x4 acc[2];
    acc[0] = (f32x4){0.f, 0.f, 0.f, 0.f};
    acc[1] = (f32x4){0.f, 0.f, 0.f, 0.f};
#pragma unroll
    for (int ks = 0; ks < 5; ++ks) {
      f16x8 af = *(const f16x8*)(abase + ks * 32);
#pragma unroll
      for (int nt = 0; nt < 2; ++nt) {
        f16x8 bf = *(const f16x8*)(bbase + (size_t)ks * bstep + nt * 128);
        acc[nt] = mfma16(af, bf, acc[nt]);
      }
    }
#pragma unroll
    for (int nt = 0; nt < 2; ++nt)
#pragma unroll
      for (int rg = 0; rg < 4; ++rg) {
        int m = quad * 4 + rg;
        if (m < 8) {
          size_t idx = (size_t)(8 + m) * BS + b0 + nt * 16 + l15;
          Zg6[idx] += acc[nt][rg];
        }
      }
  }
}

// ---------------------------------------------------------------------------
// seq_block (R7 shape: 8-spin sub-block, window 160, single wave, BT=16 rows):
// per t: L1 (2 Ksteps) -> L2..L5 (5 Ksteps + f16 Zg at coff) -> z6 (5 Ksteps,
// + Zg6 at toff) -> sample. LDS 29.2KB -> 5 WG/CU, 1024 WGs = 1 round.
// ---------------------------------------------------------------------------
__global__ __launch_bounds__(64, 1) void seq_block(
    const f16* __restrict__ Wsq, const f16* __restrict__ W1sq,
    const f16* __restrict__ W6p, f16* __restrict__ AH,
    const f16* __restrict__ Zg, const float* __restrict__ Zg6,
    f16* __restrict__ s_ws, const float* __restrict__ u,
    float* __restrict__ outp, int I, int coff, int toff, int BS, int b0) {
  __shared__ __align__(16) f16 aL[5][BT][168];   // 26880 B
  __shared__ __align__(16) f16 sL[BT][72];       // 2304 B -> 29184 total

  const int lane = threadIdx.x;
  const int l15 = lane & 15;
  const int quad = lane >> 4;
  const int r = l15;
  const int brel = blockIdx.x * BT + r;
  const int bg = b0 + brel;

  // zero LDS (unwritten regions must multiply as exact 0)
  {
    f16x8 z = {};
    f16x8* pa = (f16x8*)&aL[0][0][0];
    for (int k = lane; k < (5 * BT * 168) / 8; k += 64) pa[k] = z;
    f16x8* ps = (f16x8*)&sL[0][0];
    for (int k = lane; k < (BT * 72) / 8; k += 64) ps[k] = z;
  }
  __syncthreads();

  // sampled-bit history j < I
  {
    const int nck = I >> 3;
    for (int idx = lane; idx < BT * nck; idx += 64) {
      int rr = idx & 15, c8 = idx >> 4;
      *(f16x8*)&sL[rr][c8 * 8] =
          *(const f16x8*)(s_ws + (size_t)(blockIdx.x * BT + rr) * NS + c8 * 8);
    }
  }

  // prefetch z6 history + u thresholds (off critical path)
  float z6h[8], uu[8];
#pragma unroll
  for (int t = 0; t < 8; ++t) z6h[t] = Zg6[(size_t)(toff + t) * BS + brel];
#pragma unroll
  for (int t = 0; t < 8; ++t) uu[t] = u[(size_t)(I + t) * NB + bg];
  __syncthreads();

#pragma unroll 1
  for (int t = 0; t < 8; ++t) {
    const int i = I + t;

    // ---- layer 1: A = W1sq[i] (2 M-tiles), B = sL (K=64) ----
    {
      const f16* a0 = W1sq + ((size_t)i * 32 + l15) * 64 + quad * 8;
      f16x8 b0v = *(const f16x8*)&sL[r][quad * 8];
      f16x8 b1v = *(const f16x8*)&sL[r][32 + quad * 8];
      f16x8 a00 = *(const f16x8*)(a0);
      f16x8 a01 = *(const f16x8*)(a0 + 32);
      f16x8 a10 = *(const f16x8*)(a0 + 16 * 64);
      f16x8 a11 = *(const f16x8*)(a0 + 16 * 64 + 32);
      f32x4 acc0 = {0.f, 0.f, 0.f, 0.f}, acc1 = {0.f, 0.f, 0.f, 0.f};
      acc0 = mfma16(a00, b0v, acc0);
      acc0 = mfma16(a01, b1v, acc0);
      acc1 = mfma16(a10, b0v, acc1);
      acc1 = mfma16(a11, b1v, acc1);
      f16x4 v0;
#pragma unroll
      for (int rg = 0; rg < 4; ++rg) v0[rg] = (f16)sigm(acc0[rg]);
      *(f16x4*)&aL[0][r][t * HC + quad * 4] = v0;
      if (quad == 0) {
        f16x4 v1;
#pragma unroll
        for (int rg = 0; rg < 4; ++rg) v1[rg] = (f16)sigm(acc1[rg]);
        *(f16x4*)&aL[0][r][t * HC + 16] = v1;
      }
    }
    __syncthreads();

    // ---- layers 2..5: A = Wsq[L][i], B = aL[L], + f16 Zg at chain end ----
#pragma unroll 1
    for (int L = 0; L < 4; ++L) {
      float zin0[4], zin1[4];
#pragma unroll
      for (int rg = 0; rg < 4; ++rg)
        zin0[rg] =
            (float)Zg[(size_t)(L * 320 + coff + t * HC + quad * 4 + rg) * BS + brel];
#pragma unroll
      for (int rg = 0; rg < 4; ++rg)
        zin1[rg] =
            (float)Zg[(size_t)(L * 320 + coff + t * HC + 16 + quad * 4 + rg) * BS + brel];
      const f16* abase = Wsq + (((size_t)L * 64 + i) * 32 + l15) * 160;
      const f16* lrow = &aL[L][r][0];
      f32x4 acc0 = {0.f, 0.f, 0.f, 0.f}, acc1 = {0.f, 0.f, 0.f, 0.f};
#pragma unroll
      for (int ks = 0; ks < 5; ++ks) {
        f16x8 bv = *(const f16x8*)(lrow + ks * 32 + quad * 8);
        f16x8 a0 = *(const f16x8*)(abase + ks * 32 + quad * 8);
        f16x8 a1 = *(const f16x8*)(abase + 16 * 160 + ks * 32 + quad * 8);
        acc0 = mfma16(a0, bv, acc0);
        acc1 = mfma16(a1, bv, acc1);
      }
      f16x4 v0;
#pragma unroll
      for (int rg = 0; rg < 4; ++rg) v0[rg] = (f16)sigm(zin0[rg] + acc0[rg]);
      *(f16x4*)&aL[L + 1][r][t * HC + quad * 4] = v0;
      if (quad == 0) {
        f16x4 v1;
#pragma unroll
        for (int rg = 0; rg < 4; ++rg) v1[rg] = (f16)sigm(zin1[rg] + acc1[rg]);
        *(f16x4*)&aL[L + 1][r][t * HC + 16] = v1;
      }
      __syncthreads();
    }

    // ---- z6 intra: A = W6p rows i+l15 (m=0 used), B = aL[4] ----
    {
      const f16* w6b = W6p + (size_t)(i + l15) * HTOT + HC * I;
      const f16* l5 = &aL[4][r][0];
      f32x4 a6 = {0.f, 0.f, 0.f, 0.f};
#pragma unroll
      for (int ks = 0; ks < 5; ++ks) {
        f16x8 bv = *(const f16x8*)(l5 + ks * 32 + quad * 8);
        f16x8 av = *(const f16x8*)(w6b + ks * 32 + quad * 8);
        a6 = mfma16(av, bv, a6);
      }
      if (quad == 0) {
        float x = sigm(a6[0] + z6h[t]);
        outp[(size_t)bg * NS + i] = x;  // final output col i == sampling-time x
        sL[r][i] = (f16)((x >= uu[t]) ? 1.0f : -1.0f);
      }
    }
    __syncthreads();
  }

  // ---- bulk writeout: aL -> AH ([L][g][b][e8]), sampled bits -> s_ws ----
  for (int w = lane; w < 5 * 20 * BT; w += 64) {
    int rr = w & 15;
    int q8 = w >> 4;
    int L = q8 / 20, x8 = q8 % 20;
    f16x8 v = *(const f16x8*)&aL[L][rr][x8 * 8];
    int gg = ((HC * I) >> 3) + x8;
    *(f16x8*)(AH + ((size_t)(L * 160 + gg) * BS + blockIdx.x * BT + rr) * 8) = v;
  }
  if (lane < BT) {
    *(f16x8*)(s_ws + (size_t)(blockIdx.x * BT + lane) * NS + I) =
        *(const f16x8*)&sL[lane][I];
  }
}

// ---------------------------------------------------------------------------
extern "C" void kernel_launch(void* const* d_in, const int* in_sizes, int n_in,
                              void* d_out, int out_size, void* d_ws, size_t ws_size,
                              hipStream_t stream) {
  (void)in_sizes; (void)n_in; (void)out_size;
  const float* u  = (const float*)d_in[1];
  const float* W1 = (const float*)d_in[2];
  const float* W2 = (const float*)d_in[3];
  const float* W3 = (const float*)d_in[4];
  const float* W4 = (const float*)d_in[5];
  const float* W5 = (const float*)d_in[6];
  const float* W6 = (const float*)d_in[7];
  float* outp = (float*)d_out;

  const size_t wpEls   = (size_t)4 * HTOT * HTOT;    // 6,553,600
  const size_t w1Els   = (size_t)HTOT * NS;          // 81,920
  const size_t w6Els   = (size_t)W6R * HTOT;         // 102,400
  const size_t wsqEls  = (size_t)4 * 64 * 32 * 160;  // 1,310,720
  const size_t w1sqEls = (size_t)64 * 32 * 64;       // 131,072
  const size_t wBytes = (wpEls + w1Els + w6Els + wsqEls + w1sqEls) * sizeof(f16);
  // per-row bytes: AH 12800 + Zg f16 2592 + Zg6 64 + s 128 = 15584
  size_t rem = (ws_size > wBytes + 4096) ? (ws_size - wBytes - 4096) : 0;
  long long bs = (long long)(rem / 15600);
  bs = (bs / 64) * 64;
  if (bs > NB) bs = NB;
  if (bs < 64) bs = 64;
  const int BS = (int)bs;

  f16* Wp   = (f16*)d_ws;
  f16* W1p  = Wp + wpEls;
  f16* W6p  = W1p + w1Els;
  f16* Wsq  = W6p + w6Els;
  f16* W1sq = Wsq + wsqEls;
  f16* AH   = W1sq + w1sqEls;                        // 5*160*BS*8 f16
  f16* Zg   = AH + (size_t)5 * 160 * BS * 8;         // ZGROWS*BS f16
  float* Zg6 = (float*)(Zg + (size_t)ZGROWS * BS);   // 16*BS f32
  f16* s_ws  = (f16*)(Zg6 + (size_t)16 * BS);        // BS*64 f16

  prep1<<<dim3(4 * HTOT + 320 + W6R), dim3(256), 0, stream>>>(
      W1, W2, W3, W4, W5, W6, Wp, W1p, W6p);
  prep2<<<dim3(256 + 64), dim3(256), 0, stream>>>(Wp, W1p, Wsq, W1sq);

  for (int c0 = 0; c0 < NB; c0 += BS) {
    int nr = NB - c0; if (nr > BS) nr = BS;
    for (int m = 0; m < 4; ++m) {
      const int I = 16 * m;
      gemm_full<<<dim3(nr / 64, 5), dim3(256), 0, stream>>>(
          Wp, W6p, AH, Zg, Zg6, I, BS);
      seq_block<<<dim3(nr / BT), dim3(64), 0, stream>>>(
          Wsq, W1sq, W6p, AH, Zg, Zg6, s_ws, u, outp, I, 0, 0, BS, c0);
      gemm_mid<<<dim3(nr / 64, 5), dim3(128), 0, stream>>>(
          Wp, W6p, AH, Zg, Zg6, I, BS);
      seq_block<<<dim3(nr / BT), dim3(64), 0, stream>>>(
          Wsq, W1sq, W6p, AH, Zg, Zg6, s_ws, u, outp, I + 8, 160, 8, BS, c0);
    }
  }
}